// Round 7
// baseline (2193.911 us; speedup 1.0000x reference)
//
#include <hip/hip_runtime.h>

typedef __attribute__((ext_vector_type(8))) short bf16x8;
typedef __attribute__((ext_vector_type(4))) float f32x4;

#define NB 16384
#define NK 2048
#define ND 1000
#define KP 1024            // padded K
#define PBLK 256           // persistent sinkhorn blocks (co-resident)

__device__ float  g_dist[(size_t)NB * NK];          // 128 MiB
__device__ ushort g_E[(size_t)NB * NK];             // 64 MiB fp16 e' = exp(-2d)*8192
__device__ ushort g_Fh[(size_t)NB * KP], g_Fl[(size_t)NB * KP];   // pre-swizzled
__device__ ushort g_Ch[(size_t)NK * KP], g_Cl[(size_t)NK * KP];
__device__ float  g_u[NK], g_c2[NK];
__device__ float  g_f2[NB], g_bd[NB];
__device__ float  g_part[(size_t)PBLK * NK];        // 2 MiB
__device__ int    g_cc[NK], g_rc[NK];
__device__ uint   g_bar_count, g_bar_gen;           // grid barrier state (.bss)

typedef const __attribute__((address_space(1))) void gvoid_t;
typedef __attribute__((address_space(3))) void lvoid_t;

union h16 { ushort u; _Float16 h; };

__device__ __forceinline__ ushort bf16_rne(float x){
    uint u = __float_as_uint(x);
    uint lsb = (u >> 16) & 1u;
    u += 0x7fffu + lsb;
    return (ushort)(u >> 16);
}
__device__ __forceinline__ float bf16_to_f(ushort h){
    return __uint_as_float(((uint)h) << 16);
}

__device__ __forceinline__ float aload(const float* p){
    return __hip_atomic_load(p, __ATOMIC_RELAXED, __HIP_MEMORY_SCOPE_AGENT);
}
__device__ __forceinline__ void astore(float* p, float v){
    __hip_atomic_store(p, v, __ATOMIC_RELAXED, __HIP_MEMORY_SCOPE_AGENT);
}

// device-scope sense-reversing grid barrier (all PBLK blocks co-resident)
__device__ __forceinline__ void grid_sync(){
    __syncthreads();                    // drains all block stores to L2 (vmcnt0 before s_barrier)
    if (threadIdx.x == 0){
        __threadfence();                // device-visibility of this block's writes
        uint gen = __hip_atomic_load(&g_bar_gen, __ATOMIC_RELAXED, __HIP_MEMORY_SCOPE_AGENT);
        uint prev = __hip_atomic_fetch_add(&g_bar_count, 1u, __ATOMIC_ACQ_REL, __HIP_MEMORY_SCOPE_AGENT);
        if (prev == gridDim.x - 1){
            __hip_atomic_store(&g_bar_count, 0u, __ATOMIC_RELAXED, __HIP_MEMORY_SCOPE_AGENT);
            __hip_atomic_fetch_add(&g_bar_gen, 1u, __ATOMIC_ACQ_REL, __HIP_MEMORY_SCOPE_AGENT);
        } else {
            while (__hip_atomic_load(&g_bar_gen, __ATOMIC_ACQUIRE, __HIP_MEMORY_SCOPE_AGENT) == gen)
                __builtin_amdgcn_s_sleep(2);
        }
        __threadfence();                // invalidate L1 before post-barrier reads
    }
    __syncthreads();
}

// ---------------- prep: fp32 -> (hi,lo) bf16 split, K-pad, XOR-swizzled layout,
// fused row-sumsq ----------------
template<int WHICH>
__global__ __launch_bounds__(256) void cn_prep(const float* __restrict__ X){
    ushort* __restrict__ H = WHICH ? g_Ch : g_Fh;
    ushort* __restrict__ L = WHICH ? g_Cl : g_Fl;
    float*  __restrict__ sq = WHICH ? g_c2 : g_f2;
    const int row = blockIdx.x, t = threadIdx.x;
    const int lane = t & 63, wid = t >> 6;
    float4 x = make_float4(0.f,0.f,0.f,0.f);
    if (t < 250) x = *(const float4*)(X + (size_t)row * ND + 4 * t);
    double s = (double)x.x*x.x + (double)x.y*x.y + (double)x.z*x.z + (double)x.w*x.w;
    ushort4 h4, l4;
#pragma unroll
    for (int c = 0; c < 4; ++c){
        float xc = (&x.x)[c];
        ushort h = bf16_rne(xc);
        (&h4.x)[c] = h;
        (&l4.x)[c] = bf16_rne(xc - bf16_to_f(h));
    }
    const int base = (t >> 3) << 5;
    const int grp  = (t >> 1) & 3;
    const int pos  = base + ((grp ^ ((row >> 1) & 3)) << 3) + ((4 * t) & 7);
    *(ushort4*)&H[(size_t)row * KP + pos] = h4;
    *(ushort4*)&L[(size_t)row * KP + pos] = l4;

    __shared__ double pr[4];
    for (int off = 32; off; off >>= 1) s += __shfl_xor(s, off);
    if (lane == 0) pr[wid] = s;
    __syncthreads();
    if (t == 0) sq[row] = (float)(pr[0] + pr[1] + pr[2] + pr[3]);
}

// ---------------- split-bf16 MFMA distance GEMM, global_load_lds staging ----------------
__global__ __launch_bounds__(256) void cn_gemm_dist(){
    __shared__ __attribute__((aligned(16))) ushort Ah[128 * 32];
    __shared__ __attribute__((aligned(16))) ushort Al[128 * 32];
    __shared__ __attribute__((aligned(16))) ushort Bh[128 * 32];
    __shared__ __attribute__((aligned(16))) ushort Bl[128 * 32];

    const int tid = threadIdx.x;
    const int lane = tid & 63, wid = tid >> 6;
    const int wr = wid >> 1, wc = wid & 1;
    const int brow0 = blockIdx.y * 128, bcol0 = blockIdx.x * 128;

    f32x4 acc[4][4];
#pragma unroll
    for (int m = 0; m < 4; ++m)
#pragma unroll
        for (int n = 0; n < 4; ++n) acc[m][n] = (f32x4){0.f,0.f,0.f,0.f};

    const int lrow = lane >> 2;
    const int lcol = (lane & 3) * 8;

    for (int step = 0; step < 32; ++step){
        const int k0 = step * 32;
#pragma unroll
        for (int i = 0; i < 2; ++i){
            const int ch = wid * 2 + i;
            const int ldso = ch * 512;
            const size_t ga = ((size_t)(brow0 + ch * 16 + lrow)) * KP + k0 + lcol;
            const size_t gb = ((size_t)(bcol0 + ch * 16 + lrow)) * KP + k0 + lcol;
            __builtin_amdgcn_global_load_lds((gvoid_t*)(g_Fh + ga), (lvoid_t*)(Ah + ldso), 16, 0, 0);
            __builtin_amdgcn_global_load_lds((gvoid_t*)(g_Fl + ga), (lvoid_t*)(Al + ldso), 16, 0, 0);
            __builtin_amdgcn_global_load_lds((gvoid_t*)(g_Ch + gb), (lvoid_t*)(Bh + ldso), 16, 0, 0);
            __builtin_amdgcn_global_load_lds((gvoid_t*)(g_Cl + gb), (lvoid_t*)(Bl + ldso), 16, 0, 0);
        }
        __syncthreads();

        const int arow = wr * 64 + (lane & 15);
        const int brow = wc * 64 + (lane & 15);
        const int kof  = (((lane >> 4) ^ ((lane >> 1) & 3)) * 8);
        bf16x8 afh[4], afl[4], bfh[4], bfl[4];
#pragma unroll
        for (int m = 0; m < 4; ++m){
            afh[m] = *(const bf16x8*)&Ah[(arow + m * 16) * 32 + kof];
            afl[m] = *(const bf16x8*)&Al[(arow + m * 16) * 32 + kof];
        }
#pragma unroll
        for (int n = 0; n < 4; ++n){
            bfh[n] = *(const bf16x8*)&Bh[(brow + n * 16) * 32 + kof];
            bfl[n] = *(const bf16x8*)&Bl[(brow + n * 16) * 32 + kof];
        }
#pragma unroll
        for (int m = 0; m < 4; ++m)
#pragma unroll
            for (int n = 0; n < 4; ++n){
                acc[m][n] = __builtin_amdgcn_mfma_f32_16x16x32_bf16(afh[m], bfh[n], acc[m][n], 0, 0, 0);
                acc[m][n] = __builtin_amdgcn_mfma_f32_16x16x32_bf16(afh[m], bfl[n], acc[m][n], 0, 0, 0);
                acc[m][n] = __builtin_amdgcn_mfma_f32_16x16x32_bf16(afl[m], bfh[n], acc[m][n], 0, 0, 0);
            }
        __syncthreads();
    }

#pragma unroll
    for (int m = 0; m < 4; ++m){
        int rowb = brow0 + wr * 64 + m * 16 + (lane >> 4) * 4;
#pragma unroll
        for (int n = 0; n < 4; ++n){
            int col = bcol0 + wc * 64 + n * 16 + (lane & 15);
            float c2v = g_c2[col];
#pragma unroll
            for (int j = 0; j < 4; ++j){
                float d2 = g_f2[rowb + j] + c2v - 2.0f * acc[m][n][j];
                float d  = sqrtf(fmaxf(d2, 0.0f));
                size_t idx = (size_t)(rowb + j) * NK + col;
                g_dist[idx] = d;
                h16 cv; cv.h = (_Float16)(__expf(-2.0f * d) * 8192.0f);
                g_E[idx] = cv.u;
            }
        }
    }
}

// ---------------- persistent fused sinkhorn: 16 sweeps + reductions + assign ----------------
// it 0:    fp16-e, u==1, cst=1            -> u_1
// it 1..9: fp16-e, cst=1/B                -> u_{it+1}
// it 10..14: fp32 exact tail              -> u_{it+1}
// it 15:   fp32 final + argmax(2d-ln(uK)), argmin d, bd, histograms; S -> scnt
__global__ __launch_bounds__(256) void cn_sinkhorn(float* __restrict__ out){
    const int lane = threadIdx.x & 63, wid = threadIdx.x >> 6;
    const int gtid = blockIdx.x * 256 + (int)threadIdx.x;
    const int b0 = blockIdx.x * 64 + wid * 16;

    if (gtid < NK){ g_cc[gtid] = 0; g_rc[gtid] = 0; }

    __shared__ float4 sred[3][8][64];
    __shared__ double lred[4];

    for (int it = 0; it <= 15; ++it){
        const int useW = (it >= 1);
        const int f16  = (it <= 9);
        const int fin  = (it == 15);
        const float cst = (it == 0) ? 1.0f : (1.0f / (float)NB);

        float4 uu[8], ak[8];
        if (useW){
#pragma unroll
            for (int j = 0; j < 8; ++j)
#pragma unroll
                for (int c = 0; c < 4; ++c)
                    (&uu[j].x)[c] = aload(&g_u[4 * lane + 256 * j + c]);
        }
        if (fin){
#pragma unroll
            for (int j = 0; j < 8; ++j)
#pragma unroll
                for (int c = 0; c < 4; ++c)
                    (&ak[j].x)[c] = (float)log((double)(&uu[j].x)[c] * (double)NK);
        }

        float4 S[8];
#pragma unroll
        for (int j = 0; j < 8; ++j) S[j] = make_float4(0.f,0.f,0.f,0.f);

        for (int r = 0; r < 16; ++r){
            const int b = b0 + r;
            float4 ev[8], dv[8];
            float tsum = 0.f;
            if (f16){
                const ushort* er = g_E + (size_t)b * NK + 4 * lane;
#pragma unroll
                for (int j = 0; j < 8; ++j){
                    ushort4 q4 = *(const ushort4*)(er + 256 * j);
                    float4 e4;
#pragma unroll
                    for (int c = 0; c < 4; ++c){
                        h16 cv; cv.u = (&q4.x)[c];
                        float e = (float)cv.h;
                        (&e4.x)[c] = e;
                        tsum += useW ? e * (&uu[j].x)[c] : e;
                    }
                    ev[j] = e4;
                }
            } else {
                const float* dr = g_dist + (size_t)b * NK + 4 * lane;
#pragma unroll
                for (int j = 0; j < 8; ++j){
                    float4 d4 = *(const float4*)(dr + 256 * j);
                    float4 e4;
#pragma unroll
                    for (int c = 0; c < 4; ++c){
                        float e = __expf(-2.0f * (&d4.x)[c]);
                        (&e4.x)[c] = e;
                        tsum += e * (&uu[j].x)[c];
                    }
                    ev[j] = e4;
                    if (fin) dv[j] = d4;
                }
            }
#pragma unroll
            for (int off = 32; off; off >>= 1) tsum += __shfl_xor(tsum, off);
            const float v = cst / tsum;
#pragma unroll
            for (int j = 0; j < 8; ++j){
                S[j].x += ev[j].x * v; S[j].y += ev[j].y * v;
                S[j].z += ev[j].z * v; S[j].w += ev[j].w * v;
            }

            if (fin){
                double bestT = -1.0e300; int bi = 0; float bd = 0.f;
                float rbest = 3.4e38f;   int ri = 0;
#pragma unroll
                for (int j = 0; j < 8; ++j){
#pragma unroll
                    for (int c = 0; c < 4; ++c){
                        int k = 256 * j + 4 * lane + c;
                        float d = (&dv[j].x)[c];
                        double t = 2.0 * (double)d - (double)(&ak[j].x)[c];
                        if (t > bestT){ bestT = t; bi = k; bd = d; }
                        if (d < rbest){ rbest = d; ri = k; }
                    }
                }
                for (int off = 32; off; off >>= 1){
                    double oT = __shfl_xor(bestT, off);
                    int    oi = __shfl_xor(bi, off);
                    float  od = __shfl_xor(bd, off);
                    if (oT > bestT || (oT == bestT && oi < bi)){ bestT = oT; bi = oi; bd = od; }
                    float orb = __shfl_xor(rbest, off);
                    int   ori = __shfl_xor(ri, off);
                    if (orb < rbest || (orb == rbest && ori < ri)){ rbest = orb; ri = ori; }
                }
                if (lane == 0){
                    out[1 + b] = (float)bi;
                    astore(&g_bd[b], bd);
                    atomicAdd(&g_cc[bi], 1);
                    atomicAdd(&g_rc[ri], 1);
                }
            }
        }

        // cross-wave fp32 reduce -> block partial
        if (wid > 0){
#pragma unroll
            for (int j = 0; j < 8; ++j) sred[wid - 1][j][lane] = S[j];
        }
        __syncthreads();
        if (wid == 0){
#pragma unroll
            for (int w = 0; w < 3; ++w)
#pragma unroll
                for (int j = 0; j < 8; ++j){
                    float4 o = sred[w][j][lane];
                    S[j].x += o.x; S[j].y += o.y; S[j].z += o.z; S[j].w += o.w;
                }
#pragma unroll
            for (int j = 0; j < 8; ++j)
#pragma unroll
                for (int c = 0; c < 4; ++c)
                    astore(&g_part[(size_t)blockIdx.x * NK + 4 * lane + 256 * j + c], (&S[j].x)[c]);
        }
        grid_sync();

        // phase B: 32 threads per k, fixed-order fp64 reduction over 256 chunks
        {
            const int k = gtid >> 5, sub = gtid & 31;
            double s = 0.0;
#pragma unroll
            for (int i = 0; i < 8; ++i)
                s += (double)aload(&g_part[(size_t)(sub * 8 + i) * NK + k]);
            s += __shfl_xor(s, 16); s += __shfl_xor(s, 8);
            s += __shfl_xor(s, 4);  s += __shfl_xor(s, 2);  s += __shfl_xor(s, 1);
            if (sub == 0){
                if (!fin) astore(&g_u[k], (float)((1.0 / (double)NK) / s));
                else      out[1 + NB + k] = (float)((double)NB * (double)aload(&g_u[k]) * s);
            }
        }
        grid_sync();
    }

    // epilogue: histograms + deterministic fp64 loss
    if (gtid < NK){
        out[1 + NB + NK + gtid]     = (float)g_cc[gtid];
        out[1 + NB + 2 * NK + gtid] = (float)g_rc[gtid];
    }
    if (blockIdx.x == 0){
        double s = 0.0;
        for (int b = threadIdx.x; b < NB; b += 256) s += (double)aload(&g_bd[b]);
        for (int off = 32; off; off >>= 1) s += __shfl_xor(s, off);
        if (lane == 0) lred[wid] = s;
        __syncthreads();
        if (threadIdx.x == 0)
            out[0] = (float)((lred[0] + lred[1] + lred[2] + lred[3]) / (double)NB);
    }
}

extern "C" void kernel_launch(void* const* d_in, const int* in_sizes, int n_in,
                              void* d_out, int out_size, void* d_ws, size_t ws_size,
                              hipStream_t stream){
    const float* F  = (const float*)d_in[0];
    const float* Cn = (const float*)d_in[1];
    float* out = (float*)d_out;
    (void)d_ws; (void)ws_size;

    cn_prep<0><<<NB, 256, 0, stream>>>(F);
    cn_prep<1><<<NK, 256, 0, stream>>>(Cn);

    dim3 gg(NK / 128, NB / 128);
    cn_gemm_dist<<<gg, 256, 0, stream>>>();

    cn_sinkhorn<<<PBLK, 256, 0, stream>>>(out);
}